// Round 3
// baseline (445.015 us; speedup 1.0000x reference)
//
#include <hip/hip_runtime.h>

// Problem constants (match reference)
#define PFN_NX     512
#define PFN_NY     512
#define PFN_P      (PFN_NX * PFN_NY)     // 262144 pillars (2^18)
#define PFN_B      4
#define PFN_NPTS   100000
#define PFN_C      64
#define PFN_NBIN   (PFN_B * PFN_P)       // 1,048,576 (b,pillar) bins
#define PFN_TOTPTS (PFN_B * PFN_NPTS)    // 400,000 points
#define PFN_QCAP   512                   // LDS work-queue capacity (batched)

typedef float f32x4 __attribute__((ext_vector_type(4)));  // native vec for nt-store

// Workspace layout (ints):
//   head [NBIN]    : per-(b,pillar) list head, -1 = empty  (memset 0xFF)
//   nxt  [TOTPTS]  : next-point link per point id
//
// R8: gather restructure. R7's inner loop was a 16-way masked unroll per
// round (16 branches + 16 shfl + 16 LDS RMW per round per wave) -> issue
// bound at ~2.3 TB/s effective. Now: wave 0's 64 lanes walk all 64 lists in
// parallel ONCE, pushing (pi<<6|col) into an LDS queue; then all 4 waves
// drain the queue with lane=channel, 8-deep prefetch of independent 256 B
// x-row loads, and ds_add_f32 (LDS float atomic, no-return) into
// tile[lane][col]. Bank = (lane+col)%32 with the +1 pad -> 2-way, free.
// Per-point cost: 1 coalesced load + 1 LDS atomic (vs ~16 masked wave-ops).

__global__ __launch_bounds__(256) void pfn_build(const int* __restrict__ idx,
                                                 int* __restrict__ head,
                                                 int* __restrict__ nxt) {
    int pi = blockIdx.x * 256 + threadIdx.x;
    if (pi >= PFN_TOTPTS) return;
    int b  = (unsigned)pi / PFN_NPTS;
    int bp = b * PFN_P + idx[pi];
    nxt[pi] = atomicExch(&head[bp], pi);   // coalesced store + 1 atomic/point
}

__global__ __launch_bounds__(256) void pfn_gather(const float* __restrict__ x,
                                                  const int*   __restrict__ head,
                                                  const int*   __restrict__ nxt,
                                                  float*       __restrict__ out) {
    __shared__ float tile[64][65];       // [channel][local pillar], +1 pad
    __shared__ int   q[PFN_QCAP];        // packed (pi<<6)|col work items
    __shared__ int   qcnt;

    const int g    = blockIdx.x;         // [0, NBIN/64)
    const int bp0  = g << 6;
    const int b    = bp0 >> 18;          // / P
    const int p0   = bp0 & (PFN_P - 1);
    const int tid  = threadIdx.x;
    const int wave = tid >> 6;
    const int lane = tid & 63;

    // cooperative zero of the 64x64 live region (2-way banks, free)
    for (int k = tid; k < 64 * 64; k += 256) tile[k >> 6][k & 63] = 0.f;

    // lane j of wave 0 walks the list of bin bp0+j
    int cur = -1;
    if (tid < 64) cur = head[bp0 + tid];

    while (true) {
        if (tid == 0) qcnt = 0;
        __syncthreads();                 // also orders tile zeroing before adds

        // --- push phase: 64 parallel walkers fill the queue ---
        while (cur >= 0) {
            int slot = atomicAdd(&qcnt, 1);
            if (slot >= PFN_QCAP) break; // queue full: keep cur for next batch
            q[slot] = (cur << 6) | tid;  // pi < 2^19, col = tid (0..63)
            cur = nxt[cur];
        }
        __syncthreads();
        const int n = min(qcnt, PFN_QCAP);

        // --- drain phase: 4 waves, 8-deep independent-load prefetch ---
        for (int t0 = wave; t0 < n; t0 += 4 * 8) {
            float pre[8];
            int   col[8];
#pragma unroll
            for (int k = 0; k < 8; ++k) {
                const int t = t0 + 4 * k;
                if (t < n) {
                    const int e = q[t];          // uniform LDS broadcast
                    col[k] = e & 63;
                    pre[k] = x[((size_t)(e >> 6) << 6) + lane];  // 256 B row
                }
            }
#pragma unroll
            for (int k = 0; k < 8; ++k) {
                const int t = t0 + 4 * k;
                if (t < n) atomicAdd(&tile[lane][col[k]], pre[k]); // ds_add_f32
            }
        }
        // barrier doubles as "all adds of this batch done"
        if (!__syncthreads_or(cur >= 0)) break;
    }

    // epilogue: 1024 float4 nt-stores, 4 per thread; 16 lanes cover one
    // channel row (256 B contiguous), 4 channels per wave per iteration.
    const size_t outBase = (size_t)b << 24;          // b * 64 * P
#pragma unroll
    for (int k = 0; k < 4; ++k) {
        const int id = k * 256 + tid;                // [0, 1024)
        const int c  = id >> 4;                      // channel
        const int i  = id & 15;                      // float4 index in p
        f32x4 v;
        v.x = tile[c][4 * i + 0];
        v.y = tile[c][4 * i + 1];
        v.z = tile[c][4 * i + 2];
        v.w = tile[c][4 * i + 3];
        __builtin_nontemporal_store(
            v, (f32x4*)(out + outBase + ((size_t)c << 18) + p0 + 4 * i));
    }
}

extern "C" void kernel_launch(void* const* d_in, const int* in_sizes, int n_in,
                              void* d_out, int out_size, void* d_ws, size_t ws_size,
                              hipStream_t stream) {
    const float* x   = (const float*)d_in[0];   // (B, N, C) f32
    const int*   idx = (const int*)  d_in[1];   // (B, N) int32
    float*       out = (float*)d_out;           // (B, C, NX, NY) f32

    int* head = (int*)d_ws;                     // [NBIN]
    int* nxt  = head + PFN_NBIN;                // [TOTPTS]

    // 1) head = -1 everywhere (ws is poisoned to 0xAA each launch)
    (void)hipMemsetAsync(head, 0xFF, (size_t)PFN_NBIN * sizeof(int), stream);
    // 2) chain points into per-bin linked lists (1 atomic/point)
    pfn_build<<<(PFN_TOTPTS + 255) / 256, 256, 0, stream>>>(idx, head, nxt);
    // 3) walk lists (parallel walkers) -> LDS queue -> ds_add_f32 scatter ->
    //    single coalesced nontemporal float4 write of the whole grid
    pfn_gather<<<PFN_NBIN / 64, 256, 0, stream>>>(x, head, nxt, out);
}

// Round 4
// 363.354 us; speedup vs baseline: 1.2247x; 1.2247x over previous
//
#include <hip/hip_runtime.h>

// Problem constants (match reference)
#define PFN_NX     512
#define PFN_NY     512
#define PFN_P      (PFN_NX * PFN_NY)     // 262144 pillars (2^18)
#define PFN_B      4
#define PFN_NPTS   100000
#define PFN_C      64
#define PFN_NBIN   (PFN_B * PFN_P)       // 1,048,576 (b,pillar) bins
#define PFN_TOTPTS (PFN_B * PFN_NPTS)    // 400,000 points

typedef float f32x4 __attribute__((ext_vector_type(4)));  // native vec for nt-store

// Workspace layout (ints):
//   head [NBIN]    : per-(b,pillar) list head, -1 = empty  (memset 0xFF)
//   nxt  [TOTPTS]  : next-point link per point id
//
// R9: revert to R7's barrier-free per-wave-16-bin walk (R8's queue+barrier
// structure serialized: 185us gather, VALUBusy 11.6%). Two changes vs R7:
//  1. REGISTER accumulation acc[16] (static unroll index -> VGPRs, no LDS
//     RMW in the loop, no tile zeroing; tile written once at the end).
//  2. Chain unroll x2: process cur and nxt[cur] per round -> 32 independent
//     x-row loads in flight per wave, half the round overhead.

__global__ __launch_bounds__(256) void pfn_build(const int* __restrict__ idx,
                                                 int* __restrict__ head,
                                                 int* __restrict__ nxt) {
    int pi = blockIdx.x * 256 + threadIdx.x;
    if (pi >= PFN_TOTPTS) return;
    int b  = (unsigned)pi / PFN_NPTS;
    int bp = b * PFN_P + idx[pi];
    nxt[pi] = atomicExch(&head[bp], pi);   // coalesced store + 1 atomic/point
}

// ---------------------------------------------------------------------------
// Gather: one workgroup per 64 consecutive bins; wave owns 16 bins,
// lane = channel (256 B coalesced x reads). No barriers in the walk loop.
// ---------------------------------------------------------------------------
__global__ __launch_bounds__(256) void pfn_gather(const float* __restrict__ x,
                                                  const int*   __restrict__ head,
                                                  const int*   __restrict__ nxt,
                                                  float*       __restrict__ out) {
    __shared__ float tile[64][65];       // [channel][local pillar], +1 pad
    const int g    = blockIdx.x;         // [0, NBIN/64)
    const int bp0  = g << 6;
    const int b    = bp0 >> 18;          // / P
    const int p0   = bp0 & (PFN_P - 1);
    const int wave = threadIdx.x >> 6;
    const int lane = threadIdx.x & 63;
    const int wb0  = bp0 + wave * 16;    // this wave's first bin

    // lane j < 16 walks the list of bin wb0+j
    int cur = -1;
    if (lane < 16) cur = head[wb0 + lane];

    float acc[16];
#pragma unroll
    for (int j = 0; j < 16; ++j) acc[j] = 0.f;

    unsigned long long m0;
    while ((m0 = __ballot(cur >= 0)) != 0ull) {
        // chain hops issued first; latency hides under x processing
        int n1 = (cur >= 0) ? nxt[cur] : -1;
        unsigned long long m1 = __ballot(n1 >= 0);
        int n2 = (n1 >= 0) ? nxt[n1] : -1;

        // up to 32 INDEPENDENT 256 B x-row loads (static reg indices)
        float pre0[16], pre1[16];
#pragma unroll
        for (int j = 0; j < 16; ++j) {
            if ((m0 >> j) & 1ull) {                 // wave-uniform branch
                const int pi = __shfl(cur, j);      // broadcast bin j's point
                pre0[j] = x[((size_t)pi << 6) + lane];
            }
        }
#pragma unroll
        for (int j = 0; j < 16; ++j) {
            if ((m1 >> j) & 1ull) {
                const int pi = __shfl(n1, j);
                pre1[j] = x[((size_t)pi << 6) + lane];
            }
        }
        // pure-VGPR accumulate (no LDS in the loop)
#pragma unroll
        for (int j = 0; j < 16; ++j) {
            if ((m0 >> j) & 1ull) acc[j] += pre0[j];
        }
#pragma unroll
        for (int j = 0; j < 16; ++j) {
            if ((m1 >> j) & 1ull) acc[j] += pre1[j];
        }
        cur = n2;
    }

    // single LDS write per (lane, bin); every column written by its owner wave
#pragma unroll
    for (int j = 0; j < 16; ++j) tile[lane][wave * 16 + j] = acc[j];
    __syncthreads();

    // epilogue: 1024 float4 nt-stores, 4 per thread; 16 lanes cover one
    // channel row (256 B contiguous), 4 channels per wave per iteration.
    const size_t outBase = (size_t)b << 24;          // b * 64 * P
#pragma unroll
    for (int k = 0; k < 4; ++k) {
        const int id = k * 256 + threadIdx.x;        // [0, 1024)
        const int c  = id >> 4;                      // channel
        const int i  = id & 15;                      // float4 index in p
        f32x4 v;
        v.x = tile[c][4 * i + 0];
        v.y = tile[c][4 * i + 1];
        v.z = tile[c][4 * i + 2];
        v.w = tile[c][4 * i + 3];
        __builtin_nontemporal_store(
            v, (f32x4*)(out + outBase + ((size_t)c << 18) + p0 + 4 * i));
    }
}

extern "C" void kernel_launch(void* const* d_in, const int* in_sizes, int n_in,
                              void* d_out, int out_size, void* d_ws, size_t ws_size,
                              hipStream_t stream) {
    const float* x   = (const float*)d_in[0];   // (B, N, C) f32
    const int*   idx = (const int*)  d_in[1];   // (B, N) int32
    float*       out = (float*)d_out;           // (B, C, NX, NY) f32

    int* head = (int*)d_ws;                     // [NBIN]
    int* nxt  = head + PFN_NBIN;                // [TOTPTS]

    // 1) head = -1 everywhere (ws is poisoned to 0xAA each launch)
    (void)hipMemsetAsync(head, 0xFF, (size_t)PFN_NBIN * sizeof(int), stream);
    // 2) chain points into per-bin linked lists (1 atomic/point)
    pfn_build<<<(PFN_TOTPTS + 255) / 256, 256, 0, stream>>>(idx, head, nxt);
    // 3) walk lists + register-accumulate + LDS transpose + nt float4 write
    pfn_gather<<<PFN_NBIN / 64, 256, 0, stream>>>(x, head, nxt, out);
}